// Round 10
// baseline (1398.540 us; speedup 1.0000x reference)
//
#include <hip/hip_runtime.h>
#include <hip/hip_fp8.h>

// Problem constants
#define NB   2048   // batch
#define SEQ  168    // encoder steps
#define NF   7      // features
#define NH   128    // hidden
#define NP   96     // decoder steps
#define EROWS 8     // encoder rows/block -> 256 blocks
#define DROWS 4     // decoder rows/block -> 512 blocks (2 passes; hist LDS-resident)
#define NTHR 512
#define KE   160    // enc A/B K: [x 0..6][pad 7][h 8..135][pad 136..159]
#define KD   256    // dec A/B K: [combine 0..127][prev_h 128..255]
#define HXS  168    // h16 row stride for enc MFMA-A tile
#define CTS  264    // cath row stride in h16

#define L2E      1.4426950408889634f
#define TWO_L2E  2.8853900817779268f

typedef _Float16 h16;
typedef _Float16 h16x8 __attribute__((ext_vector_type(8)));
typedef float    f32x2 __attribute__((ext_vector_type(2)));
typedef float    f32x4 __attribute__((ext_vector_type(4)));
typedef unsigned int u32x4 __attribute__((ext_vector_type(4)));

// -------- d_ws layout (bytes). Total ~45.6 MB. --------
constexpr size_t WENC_OFF   = 0;         // h16[512][160] (log2e-folded)
constexpr size_t WDEC_OFF   = 163840;    // h16[512][256] (log2e-folded)
constexpr size_t WEFF_OFF   = 425984;    // h16[168][128]  log2e*(W_att_h + W_out^T W_att_y)
constexpr size_t BEFF_OFF   = 468992;    // f32[168] (log2e-folded)
constexpr size_t WCOMB_OFF  = 469760;    // f32[128]  W_out^T @ W_fin^T
constexpr size_t BCONST_OFF = 470272;    // f32[1]
constexpr size_t BENC_OFF   = 470528;    // f32[512] (log2e-folded)
constexpr size_t BDEC_OFF   = 472576;    // f32[512] (log2e-folded)
constexpr size_t ENC_OFF    = 524288;    // u32[NB][42][128]: fp8x4 (s-packed) hist, x16 scale
constexpr size_t HT_OFF     = 44564480;  // f32[NB*NH] final encoder h (1 MB)

// -------- decoder dynamic-LDS layout (bytes) --------
constexpr int HIST_OFF = 0;        // uint2[4][21][128] (s-pair-major) 86016
constexpr int CATH_OFF = 86016;    // h16[2][16][CTS]   16896 -> 102912
constexpr int ATTW_OFF = 102912;   // f32[4][168] e-vals 2688 -> 105600
constexpr int WAT2_OFF = 105600;   // h16[40][128] Weff tail 10240 -> 115840
constexpr int D0_OFF   = 115840;   // f32[4][168] step-0 delta 2688 -> 118528
constexpr int OUTP_OFF = 118528;   // f32[8][4] out partials 128 -> 118656
constexpr int YH_OFF   = 118656;   // f32[28] 128 -> 118784
constexpr int Z_OFF    = 118784;   // f32[2][4] softmax denom 32 -> 118816
constexpr int DSMEM    = 118816;

__device__ __forceinline__ float sigm2(float y) { return 1.f / (1.f + exp2f(-y)); }  // y=log2e*x
__device__ __forceinline__ float tanh2(float y) {  // y = 2*log2e*x
  float e = exp2f(-fabsf(y));
  return copysignf((1.f - e) / (1.f + e), y);
}

template <bool HI>
__device__ __forceinline__ unsigned int pack2_fp8(float a, float b, unsigned int old) {
#if __has_builtin(__builtin_amdgcn_cvt_pk_fp8_f32)
  return (unsigned int)__builtin_amdgcn_cvt_pk_fp8_f32(a, b, (int)old, HI);
#else
  __hip_fp8_e4m3 qa(a), qb(b);
  unsigned int pair = (unsigned int)(*(unsigned char*)&qa) |
                      ((unsigned int)(*(unsigned char*)&qb) << 8);
  return HI ? ((old & 0x0000ffffu) | (pair << 16)) : ((old & 0xffff0000u) | pair);
#endif
}
template <bool HI>
__device__ __forceinline__ f32x2 unp2(unsigned int w) {
#if __has_builtin(__builtin_amdgcn_cvt_pk_f32_fp8)
  return __builtin_amdgcn_cvt_pk_f32_fp8(w, HI);
#else
  __hip_fp8_e4m3 a, b;
  constexpr unsigned int sh = HI ? 16 : 0;
  *(unsigned char*)&a = (w >> sh) & 0xff;
  *(unsigned char*)&b = (w >> (sh + 8)) & 0xff;
  f32x2 r; r.x = (float)a; r.y = (float)b; return r;
#endif
}

// -------- setup: cast/pack weights + algebraic folds (incl. log2e) into ws --------
__global__ void setup_weights(const float* __restrict__ Wih_enc, const float* __restrict__ Whh_enc,
                              const float* __restrict__ Wih_dec, const float* __restrict__ Whh_dec,
                              const float* __restrict__ Watt, const float* __restrict__ batt,
                              const float* __restrict__ Wout, const float* __restrict__ bout,
                              const float* __restrict__ Wfin, const float* __restrict__ bfin,
                              const float* __restrict__ bihe, const float* __restrict__ bhhe,
                              const float* __restrict__ bihd, const float* __restrict__ bhhd,
                              char* __restrict__ ws) {
  int idx = blockIdx.x * blockDim.x + threadIdx.x;
  constexpr int A0 = 81920;            // enc W
  constexpr int A1 = A0 + 131072;      // dec W
  constexpr int A2 = A1 + 21504;       // Weff
  constexpr int A3 = A2 + 168;         // beff
  constexpr int A4 = A3 + 128;         // wcomb
  constexpr int A5 = A4 + 1;           // bconst
  constexpr int A6 = A5 + 512;         // biases
  if (idx < A0) {
    int n = idx / KE, k = idx % KE;
    float sc = ((n >> 7) == 2) ? TWO_L2E : L2E;   // g-gate gets 2*log2e (tanh2)
    float v = 0.f;
    if (k < NF) v = Wih_enc[n * NF + k];
    else if (k >= 8 && k < 136) v = Whh_enc[n * NH + (k - 8)];
    ((h16*)(ws + WENC_OFF))[idx] = (h16)(v * sc);
  } else if (idx < A1) {
    int i = idx - A0;
    int n = i / KD, k = i % KD;
    float sc = ((n >> 7) == 2) ? TWO_L2E : L2E;
    float v = (k < NH) ? Wih_dec[n * NH + k] : Whh_dec[n * NH + (k - NH)];
    ((h16*)(ws + WDEC_OFF))[i] = (h16)(v * sc);
  } else if (idx < A2) {
    int i = idx - A1;
    int s = i / NH, k = i % NH;
    float v = Watt[s * (NH + NF) + k];
    #pragma unroll
    for (int f = 0; f < NF; ++f)
      v += Watt[s * (NH + NF) + NH + f] * Wout[f * NH + k];
    ((h16*)(ws + WEFF_OFF))[i] = (h16)(v * L2E);
  } else if (idx < A3) {
    int s = idx - A2;
    float v = batt[s];
    #pragma unroll
    for (int f = 0; f < NF; ++f)
      v += Watt[s * (NH + NF) + NH + f] * bout[f];
    ((float*)(ws + BEFF_OFF))[s] = v * L2E;
  } else if (idx < A4) {
    int k = idx - A3;
    float v = 0.f;
    #pragma unroll
    for (int f = 0; f < NF; ++f) v += Wfin[f] * Wout[f * NH + k];
    ((float*)(ws + WCOMB_OFF))[k] = v;
  } else if (idx < A5) {
    float v = bfin[0];
    #pragma unroll
    for (int f = 0; f < NF; ++f) v += bout[f] * Wfin[f];
    ((float*)(ws + BCONST_OFF))[0] = v;
  } else if (idx < A6) {
    int g = idx - A5;
    float sc = ((g >> 7) == 2) ? TWO_L2E : L2E;
    ((float*)(ws + BENC_OFF))[g] = (bihe[g] + bhhe[g]) * sc;
    ((float*)(ws + BDEC_OFF))[g] = (bihd[g] + bhhd[g]) * sc;
  }
}

// ================= encoder: 8 rows/block, 256 blocks, 1 barrier/step =================
__global__ __launch_bounds__(NTHR, 1)
void enc_kernel(const float* __restrict__ xb, const h16* __restrict__ w16enc,
                const float* __restrict__ bencp, unsigned int* __restrict__ encw,
                float* __restrict__ hT) {
  __shared__ alignas(16) h16 sh_hx[2][16][HXS];

  const int t  = threadIdx.x;
  const int r0 = blockIdx.x * EROWS;

  for (int i = t; i < 2 * 16 * HXS; i += NTHR) ((h16*)sh_hx)[i] = (h16)0.f;
  __syncthreads();
  if (t < EROWS * NF) {
    int r = t / NF, f = t - (t / NF) * NF;
    sh_hx[0][r][f] = (h16)xb[((size_t)(r0 + r) * SEQ + 0) * NF + f];
  }

  const int w  = t >> 6;
  const int l  = t & 63;
  const int lq = l >> 4;
  const int ln = l & 15;
  const int hcol = w * 16 + ln;
  const int mrow = lq * 4;
  const bool act = (lq < 2);

  const int j  = t & 3;
  const int rf = t >> 2;
  const int xr = rf / NF;
  const int xf = rf - xr * NF;

  h16x8 bfE[4][5];
  float bE[4];
  #pragma unroll
  for (int g = 0; g < 4; ++g) {
    int n = g * 128 + hcol;
    bE[g] = bencp[n];
    #pragma unroll
    for (int kt = 0; kt < 5; ++kt)
      bfE[g][kt] = *(const h16x8*)(w16enc + n * KE + kt * 32 + lq * 8);
  }

  float creg[4] = {0.f, 0.f, 0.f, 0.f};
  float hlast[4] = {0.f, 0.f, 0.f, 0.f};
  float hprev[4] = {0.f, 0.f, 0.f, 0.f};
  unsigned int hpack[4] = {0u, 0u, 0u, 0u};
  float xstash = 0.f;

  __syncthreads();

  for (int s = 0; s < SEQ; ++s) {
    const int cur = s & 1;
    if ((s & 3) == 0 && t < EROWS * NF * 4) {
      int sx = s + 1 + j;
      xstash = (sx < SEQ) ? xb[((size_t)(r0 + xr) * SEQ + sx) * NF + xf] : 0.f;
    }

    h16x8 af[5];
    #pragma unroll
    for (int kt = 0; kt < 5; ++kt)
      af[kt] = *(const h16x8*)(&sh_hx[cur][ln][kt * 32 + lq * 8]);
    f32x4 ac[4];
    #pragma unroll
    for (int g = 0; g < 4; ++g) {
      f32x4 a = {0.f, 0.f, 0.f, 0.f};
      #pragma unroll
      for (int kt = 0; kt < 5; ++kt)
        a = __builtin_amdgcn_mfma_f32_16x16x32_f16(af[kt], bfE[g][kt], a, 0, 0, 0);
      ac[g] = a;
    }

    if (act) {
      #pragma unroll
      for (int reg = 0; reg < 4; ++reg) {
        float gi = sigm2(ac[0][reg] + bE[0]);
        float gf = sigm2(ac[1][reg] + bE[1]);
        float gg = tanh2(ac[2][reg] + bE[2]);
        float go = sigm2(ac[3][reg] + bE[3]);
        float c = gf * creg[reg] + gi * gg;
        creg[reg] = c;
        float h = go * tanh2(c * TWO_L2E);
        hlast[reg] = h;
        sh_hx[cur ^ 1][mrow + reg][8 + hcol] = (h16)h;
        float hs = h * 16.f;
        if ((s & 1) == 0) hprev[reg] = hs;
        else if ((s & 3) == 1) hpack[reg] = pack2_fp8<false>(hprev[reg], hs, hpack[reg]);
        else                   hpack[reg] = pack2_fp8<true>(hprev[reg], hs, hpack[reg]);
      }
      if ((s & 3) == 3) {
        int s4 = s >> 2;
        #pragma unroll
        for (int reg = 0; reg < 4; ++reg)
          encw[((size_t)(r0 + mrow + reg) * 42 + s4) * NH + hcol] = hpack[reg];
      }
    }
    if (t < EROWS * NF * 4 && (s & 3) == j && s + 1 < SEQ)
      sh_hx[cur ^ 1][xr][xf] = (h16)xstash;
    __syncthreads();
  }

  if (act) {
    #pragma unroll
    for (int reg = 0; reg < 4; ++reg)
      hT[(size_t)(r0 + mrow + reg) * NH + hcol] = hlast[reg];
  }
}

// ================= decoder: 4 rows/block, hist in LDS (s-pair-major), 3 barriers/step ===
__global__ __launch_bounds__(NTHR, 1)
void dec_kernel(const float* __restrict__ xb, const float* __restrict__ Watt,
                const float* __restrict__ Wout, const float* __restrict__ bout,
                const h16* __restrict__ w16dec, const h16* __restrict__ weff,
                const float* __restrict__ beffp, const float* __restrict__ wcombp,
                const float* __restrict__ bconstp, const float* __restrict__ bdecp,
                const unsigned int* __restrict__ encw, const float* __restrict__ hT,
                float* __restrict__ out) {
  extern __shared__ char smem[];
  unsigned int* hist = (unsigned int*)(smem + HIST_OFF);   // uint2[4][21][128]
  h16*   sh_cath  = (h16*)(smem + CATH_OFF);
  float* sh_attw  = (float*)(smem + ATTW_OFF);
  h16*   sh_watt2 = (h16*)(smem + WAT2_OFF);
  float* sh_d0    = (float*)(smem + D0_OFF);
  float* sh_outp  = (float*)(smem + OUTP_OFF);
  float* sh_yh    = (float*)(smem + YH_OFF);
  float* sh_z     = (float*)(smem + Z_OFF);                // [2][4]

  const int t  = threadIdx.x;
  const int r0 = blockIdx.x * DROWS;

  // ---- init LDS ----
  for (int i = t; i < 2 * 16 * CTS; i += NTHR)  sh_cath[i] = (h16)0.f;
  for (int i = t; i < 40 * NH; i += NTHR)       sh_watt2[i] = weff[128 * NH + i];
  if (t < 8) sh_z[t] = 0.f;
  {
    // transpose [r][s4][h] (coalesced global) -> [r][s4>>1][h] pairs (s-pair-major LDS)
    const unsigned int* src = encw + (size_t)r0 * 42 * NH;
    for (int i = t; i < DROWS * 42 * NH; i += NTHR) {
      unsigned int v = src[i];
      int r = i / (42 * NH);
      int rem = i - r * (42 * NH);
      int s4 = rem >> 7, h = rem & 127;
      hist[((((r * 21 + (s4 >> 1)) << 7) | h) << 1) | (s4 & 1)] = v;
    }
  }

  const int w  = t >> 6;
  const int l  = t & 63;
  const int lq = l >> 4;
  const int ln = l & 15;
  const int hcol = w * 16 + ln;
  const bool act = (lq == 0);   // rows 0..3 real

  // B fragments: dec gates (i,f,g) K=256; Weff tile K=128
  h16x8 bfD[3][8];
  float bD[3];
  #pragma unroll
  for (int g = 0; g < 3; ++g) {
    int n = g * 128 + hcol;
    bD[g] = bdecp[n];
    #pragma unroll
    for (int kt = 0; kt < 8; ++kt)
      bfD[g][kt] = *(const h16x8*)(w16dec + n * KD + kt * 32 + lq * 8);
  }
  h16x8 bfA[4];
  #pragma unroll
  for (int kt = 0; kt < 4; ++kt)
    bfA[kt] = *(const h16x8*)(weff + hcol * NH + kt * 32 + lq * 8);
  const float beffR = beffp[hcol];
  const int s2v = 128 + hcol;
  const float beff2 = (w < 3 && s2v < SEQ) ? beffp[s2v] : 0.f;
  const float wcombR = wcombp[hcol];
  const float bconstv = bconstp[0];

  float creg[4] = {0.f, 0.f, 0.f, 0.f};
  if (act) {
    #pragma unroll
    for (int reg = 0; reg < 4; ++reg) {
      float hv = hT[(size_t)(r0 + reg) * NH + hcol];
      creg[reg] = hv;
      sh_cath[0 * 16 * CTS + reg * CTS + 128 + hcol] = (h16)hv;
    }
  }
  if (t < DROWS * NF) {
    int r = t / NF, f = t - (t / NF) * NF;
    float a = bout[f];
    const float* wr = Wout + f * NH;
    const float* hp = hT + (size_t)(r0 + r) * NH;
    #pragma unroll 8
    for (int k = 0; k < NH; k += 4) {
      float4 pv = *(const float4*)(hp + k);
      float4 wv = *(const float4*)(wr + k);
      a += pv.x * wv.x + pv.y * wv.y + pv.z * wv.z + pv.w * wv.w;
    }
    sh_yh[t] = a;
  }
  __syncthreads();
  if (t < DROWS * SEQ) {
    int r = t / SEQ, s = t - (t / SEQ) * SEQ;
    float a = 0.f;
    #pragma unroll
    for (int f = 0; f < NF; ++f) {
      float y0f = xb[((size_t)(r0 + r) * SEQ + (SEQ - 1)) * NF + f];
      a += (y0f - sh_yh[r * NF + f]) * Watt[s * (NH + NF) + NH + f];
    }
    sh_d0[r * SEQ + s] = a * L2E;
  }
  __syncthreads();

  // D3 per-thread constants
  const int dr = t >> 7;
  const int dh = t & 127;
  const uint2* hrow = (const uint2*)hist + ((size_t)dr * 21 << 7) + dh;
  const float* erow = sh_attw + dr * SEQ;

  for (int p = 0; p < NP; ++p) {
    const int CA = p & 1;
    const int bz = p & 1;

    if (p > 0 && t < DROWS) {
      float a = bconstv;
      #pragma unroll
      for (int w2 = 0; w2 < 8; ++w2) a += sh_outp[w2 * 4 + t];
      out[(size_t)(r0 + t) * NP + (p - 1)] = a;
    }

    // D1: logits (log2-domain) = prev_h @ Weff^T + beff (+d0 @p0); e = exp2; Z via shfl+atomic
    {
      h16x8 afA[4];
      #pragma unroll
      for (int kt = 0; kt < 4; ++kt)
        afA[kt] = *(const h16x8*)(sh_cath + CA * 16 * CTS + ln * CTS + 128 + kt * 32 + lq * 8);
      f32x4 acc = {0.f, 0.f, 0.f, 0.f};
      #pragma unroll
      for (int kt = 0; kt < 4; ++kt)
        acc = __builtin_amdgcn_mfma_f32_16x16x32_f16(afA[kt], bfA[kt], acc, 0, 0, 0);
      float e0[4] = {0.f, 0.f, 0.f, 0.f};
      float e1[4] = {0.f, 0.f, 0.f, 0.f};
      if (act) {
        #pragma unroll
        for (int reg = 0; reg < 4; ++reg) {
          float lg = acc[reg] + beffR;
          if (p == 0) lg += sh_d0[reg * SEQ + hcol];
          lg = fminf(fmaxf(lg, -43.f), 43.f);
          float e = exp2f(lg);
          e0[reg] = e;
          sh_attw[reg * SEQ + hcol] = e;
        }
      }
      if (w < 3) {
        int srow = (s2v < SEQ ? s2v : SEQ - 1) - 128;
        f32x4 acc2 = {0.f, 0.f, 0.f, 0.f};
        #pragma unroll
        for (int kt = 0; kt < 4; ++kt) {
          h16x8 bf2 = *(const h16x8*)(sh_watt2 + srow * NH + kt * 32 + lq * 8);
          acc2 = __builtin_amdgcn_mfma_f32_16x16x32_f16(afA[kt], bf2, acc2, 0, 0, 0);
        }
        if (s2v < SEQ && act) {
          #pragma unroll
          for (int reg = 0; reg < 4; ++reg) {
            float lg = acc2[reg] + beff2;
            if (p == 0) lg += sh_d0[reg * SEQ + s2v];
            lg = fminf(fmaxf(lg, -43.f), 43.f);
            float e = exp2f(lg);
            e1[reg] = e;
            sh_attw[reg * SEQ + s2v] = e;
          }
        }
      }
      if (act) {
        #pragma unroll
        for (int reg = 0; reg < 4; ++reg) {
          float es = e0[reg] + e1[reg];
          es += __shfl_xor(es, 1, 16);
          es += __shfl_xor(es, 2, 16);
          es += __shfl_xor(es, 4, 16);
          es += __shfl_xor(es, 8, 16);
          if (ln == 0) atomicAdd(&sh_z[bz * 4 + reg], es);
        }
      }
    }
    __syncthreads();

    // D3: combine[r][h] = (Σ_s e_s v_s) * 0.0625/Z; thread owns (r,h); b64 hist reads
    {
      f32x2 av = {0.f, 0.f};
      #pragma unroll 7
      for (int jj = 0; jj < 21; ++jj) {
        uint2 ev = hrow[jj << 7];
        float4 eA = *(const float4*)(erow + jj * 8);
        float4 eB = *(const float4*)(erow + jj * 8 + 4);
        f32x2 p0 = unp2<false>(ev.x);
        f32x2 p1 = unp2<true>(ev.x);
        f32x2 p2 = unp2<false>(ev.y);
        f32x2 p3 = unp2<true>(ev.y);
        av += f32x2{eA.x, eA.y} * p0;
        av += f32x2{eA.z, eA.w} * p1;
        av += f32x2{eB.x, eB.y} * p2;
        av += f32x2{eB.z, eB.w} * p3;
      }
      float inv = 0.0625f / sh_z[bz * 4 + dr];
      sh_cath[CA * 16 * CTS + dr * CTS + dh] = (h16)((av.x + av.y) * inv);
      if (t < 4) sh_z[(bz ^ 1) * 4 + t] = 0.f;   // re-zero other buffer for D1(p+1)
    }
    __syncthreads();

    // D4+D5: gates via MFMA (i,f,g); cell in-register; out-partials via wcomb
    {
      h16x8 af[8];
      #pragma unroll
      for (int kt = 0; kt < 8; ++kt)
        af[kt] = *(const h16x8*)(sh_cath + CA * 16 * CTS + ln * CTS + kt * 32 + lq * 8);
      f32x4 ag[3];
      #pragma unroll
      for (int g = 0; g < 3; ++g) {
        f32x4 a = {0.f, 0.f, 0.f, 0.f};
        #pragma unroll
        for (int kt = 0; kt < 8; ++kt)
          a = __builtin_amdgcn_mfma_f32_16x16x32_f16(af[kt], bfD[g][kt], a, 0, 0, 0);
        ag[g] = a;
      }
      if (act) {
        float contrib[4];
        #pragma unroll
        for (int reg = 0; reg < 4; ++reg) {
          float gi = sigm2(ag[0][reg] + bD[0]);
          float gf = sigm2(ag[1][reg] + bD[1]);
          float gg = tanh2(ag[2][reg] + bD[2]);
          float cn = gf * creg[reg] + gi * gg;
          creg[reg] = cn;
          sh_cath[(CA ^ 1) * 16 * CTS + reg * CTS + 128 + hcol] = (h16)cn;
          contrib[reg] = cn * wcombR;
        }
        #pragma unroll
        for (int reg = 0; reg < 4; ++reg) {
          float rsum = contrib[reg];
          rsum += __shfl_xor(rsum, 1);
          rsum += __shfl_xor(rsum, 2);
          rsum += __shfl_xor(rsum, 4);
          rsum += __shfl_xor(rsum, 8);
          if (l == 0) sh_outp[w * 4 + reg] = rsum;
        }
      }
    }
    __syncthreads();
  }

  if (t < DROWS) {
    float a = bconstv;
    #pragma unroll
    for (int w2 = 0; w2 < 8; ++w2) a += sh_outp[w2 * 4 + t];
    out[(size_t)(r0 + t) * NP + (NP - 1)] = a;
  }
}

extern "C" void kernel_launch(void* const* d_in, const int* in_sizes, int n_in,
                              void* d_out, int out_size, void* d_ws, size_t ws_size,
                              hipStream_t stream) {
  const float* xb      = (const float*)d_in[0];
  const float* Wih_enc = (const float*)d_in[1];
  const float* Whh_enc = (const float*)d_in[2];
  const float* bih_enc = (const float*)d_in[3];
  const float* bhh_enc = (const float*)d_in[4];
  const float* Watt    = (const float*)d_in[5];
  const float* batt    = (const float*)d_in[6];
  const float* Wih_dec = (const float*)d_in[7];
  const float* Whh_dec = (const float*)d_in[8];
  const float* bih_dec = (const float*)d_in[9];
  const float* bhh_dec = (const float*)d_in[10];
  const float* Wout    = (const float*)d_in[11];
  const float* bout    = (const float*)d_in[12];
  const float* Wfin    = (const float*)d_in[13];
  const float* bfin    = (const float*)d_in[14];
  char* ws = (char*)d_ws;  // needs ~45.6 MB

  hipFuncSetAttribute(reinterpret_cast<const void*>(dec_kernel),
                      hipFuncAttributeMaxDynamicSharedMemorySize, DSMEM);

  setup_weights<<<920, 256, 0, stream>>>(Wih_enc, Whh_enc, Wih_dec, Whh_dec,
                                         Watt, batt, Wout, bout, Wfin, bfin,
                                         bih_enc, bhh_enc, bih_dec, bhh_dec, ws);
  enc_kernel<<<NB / EROWS, NTHR, 0, stream>>>(
      xb, (const h16*)(ws + WENC_OFF), (const float*)(ws + BENC_OFF),
      (unsigned int*)(ws + ENC_OFF), (float*)(ws + HT_OFF));
  dec_kernel<<<NB / DROWS, NTHR, DSMEM, stream>>>(
      xb, Watt, Wout, bout,
      (const h16*)(ws + WDEC_OFF), (const h16*)(ws + WEFF_OFF),
      (const float*)(ws + BEFF_OFF), (const float*)(ws + WCOMB_OFF),
      (const float*)(ws + BCONST_OFF), (const float*)(ws + BDEC_OFF),
      (const unsigned int*)(ws + ENC_OFF), (const float*)(ws + HT_OFF),
      (float*)d_out);
}

// Round 11
// 1328.603 us; speedup vs baseline: 1.0526x; 1.0526x over previous
//
#include <hip/hip_runtime.h>
#include <hip/hip_fp8.h>

// Problem constants
#define NB   2048   // batch
#define SEQ  168    // encoder steps
#define NF   7      // features
#define NH   128    // hidden
#define NP   96     // decoder steps
#define EROWS 8     // encoder rows/block -> 256 blocks
#define DROWS 8     // decoder rows/block -> 256 blocks, SINGLE pass (96 seq steps)
#define NTHR 512
#define KE   160    // enc A/B K: [x 0..6][pad 7][h 8..135][pad 136..159]
#define KD   256    // dec A/B K: [combine 0..127][prev_h 128..255]
#define HXS  168    // h16 row stride for enc MFMA-A tile
#define CTS  264    // cath row stride in h16
#define NS4  42     // s-packs (4 s per u32)
#define NSL  24     // s-packs resident in LDS
#define NSG  18     // s-packs read from global/L2 each step

typedef _Float16 h16;
typedef _Float16 h16x2 __attribute__((ext_vector_type(2)));
typedef _Float16 h16x8 __attribute__((ext_vector_type(8)));
typedef float    f32x2 __attribute__((ext_vector_type(2)));
typedef float    f32x4 __attribute__((ext_vector_type(4)));
typedef unsigned int u32x4 __attribute__((ext_vector_type(4)));

// -------- d_ws layout (bytes). Total ~45.6 MB. --------
constexpr size_t WENC_OFF   = 0;         // h16[512][160]
constexpr size_t WDEC_OFF   = 163840;    // h16[512][256]
constexpr size_t WEFF_OFF   = 425984;    // h16[168][128]  W_att_h + W_out^T W_att_y
constexpr size_t BEFF_OFF   = 468992;    // f32[168]
constexpr size_t WCOMB_OFF  = 469760;    // f32[128]  W_out^T @ W_fin^T
constexpr size_t BCONST_OFF = 470272;    // f32[1]
constexpr size_t BENC_OFF   = 470528;    // f32[512]
constexpr size_t BDEC_OFF   = 472576;    // f32[512]
constexpr size_t ENC_OFF    = 524288;    // u32[NB][42][128]: fp8x4 (s-packed) hist, x16 scale
constexpr size_t HT_OFF     = 44564480;  // f32[NB*NH] final encoder h (1 MB)

// -------- decoder dynamic-LDS layout (bytes) --------
constexpr int HIST_OFF = 0;        // u32[8][24][128]  98304
constexpr int CATH_OFF = 98304;    // h16[2][16][CTS]  16896 -> 115200
constexpr int ATTW_OFF = 115200;   // f32[8][168]       5376 -> 120576
constexpr int WAT2_OFF = 120576;   // h16[40][128]     10240 -> 130816
constexpr int D0_OFF   = 130816;   // f32[8][168]       5376 -> 136192
constexpr int OUTP_OFF = 136192;   // f32[8][8]          256 -> 136448
constexpr int YH_OFF   = 136448;   // f32[56]            224 -> 136672
constexpr int DSMEM    = 136672;

__device__ __forceinline__ float sigm(float x) { return 1.f / (1.f + __expf(-x)); }
__device__ __forceinline__ float tanh_(float x) {
  float e = __expf(-2.f * fabsf(x));
  return copysignf((1.f - e) / (1.f + e), x);
}

template <bool HI>
__device__ __forceinline__ unsigned int pack2_fp8(float a, float b, unsigned int old) {
#if __has_builtin(__builtin_amdgcn_cvt_pk_fp8_f32)
  return (unsigned int)__builtin_amdgcn_cvt_pk_fp8_f32(a, b, (int)old, HI);
#else
  __hip_fp8_e4m3 qa(a), qb(b);
  unsigned int pair = (unsigned int)(*(unsigned char*)&qa) |
                      ((unsigned int)(*(unsigned char*)&qb) << 8);
  return HI ? ((old & 0x0000ffffu) | (pair << 16)) : ((old & 0xffff0000u) | pair);
#endif
}
template <bool HI>
__device__ __forceinline__ f32x2 unp2(unsigned int w) {
#if __has_builtin(__builtin_amdgcn_cvt_pk_f32_fp8)
  return __builtin_amdgcn_cvt_pk_f32_fp8(w, HI);
#else
  __hip_fp8_e4m3 a, b;
  constexpr unsigned int sh = HI ? 16 : 0;
  *(unsigned char*)&a = (w >> sh) & 0xff;
  *(unsigned char*)&b = (w >> (sh + 8)) & 0xff;
  f32x2 r; r.x = (float)a; r.y = (float)b; return r;
#endif
}

// -------- setup: cast/pack weights + algebraic folds into ws (R9 semantics) --------
__global__ void setup_weights(const float* __restrict__ Wih_enc, const float* __restrict__ Whh_enc,
                              const float* __restrict__ Wih_dec, const float* __restrict__ Whh_dec,
                              const float* __restrict__ Watt, const float* __restrict__ batt,
                              const float* __restrict__ Wout, const float* __restrict__ bout,
                              const float* __restrict__ Wfin, const float* __restrict__ bfin,
                              const float* __restrict__ bihe, const float* __restrict__ bhhe,
                              const float* __restrict__ bihd, const float* __restrict__ bhhd,
                              char* __restrict__ ws) {
  int idx = blockIdx.x * blockDim.x + threadIdx.x;
  constexpr int A0 = 81920;
  constexpr int A1 = A0 + 131072;
  constexpr int A2 = A1 + 21504;
  constexpr int A3 = A2 + 168;
  constexpr int A4 = A3 + 128;
  constexpr int A5 = A4 + 1;
  constexpr int A6 = A5 + 512;
  if (idx < A0) {
    int n = idx / KE, k = idx % KE;
    float v = 0.f;
    if (k < NF) v = Wih_enc[n * NF + k];
    else if (k >= 8 && k < 136) v = Whh_enc[n * NH + (k - 8)];
    ((h16*)(ws + WENC_OFF))[idx] = (h16)v;
  } else if (idx < A1) {
    int i = idx - A0;
    int n = i / KD, k = i % KD;
    float v = (k < NH) ? Wih_dec[n * NH + k] : Whh_dec[n * NH + (k - NH)];
    ((h16*)(ws + WDEC_OFF))[i] = (h16)v;
  } else if (idx < A2) {
    int i = idx - A1;
    int s = i / NH, k = i % NH;
    float v = Watt[s * (NH + NF) + k];
    #pragma unroll
    for (int f = 0; f < NF; ++f)
      v += Watt[s * (NH + NF) + NH + f] * Wout[f * NH + k];
    ((h16*)(ws + WEFF_OFF))[i] = (h16)v;
  } else if (idx < A3) {
    int s = idx - A2;
    float v = batt[s];
    #pragma unroll
    for (int f = 0; f < NF; ++f)
      v += Watt[s * (NH + NF) + NH + f] * bout[f];
    ((float*)(ws + BEFF_OFF))[s] = v;
  } else if (idx < A4) {
    int k = idx - A3;
    float v = 0.f;
    #pragma unroll
    for (int f = 0; f < NF; ++f) v += Wfin[f] * Wout[f * NH + k];
    ((float*)(ws + WCOMB_OFF))[k] = v;
  } else if (idx < A5) {
    float v = bfin[0];
    #pragma unroll
    for (int f = 0; f < NF; ++f) v += bout[f] * Wfin[f];
    ((float*)(ws + BCONST_OFF))[0] = v;
  } else if (idx < A6) {
    int g = idx - A5;
    ((float*)(ws + BENC_OFF))[g] = bihe[g] + bhhe[g];
    ((float*)(ws + BDEC_OFF))[g] = bihd[g] + bhhd[g];
  }
}

// ================= encoder: 8 rows/block, 256 blocks, 1 barrier/step (R9 verbatim) ======
__global__ __launch_bounds__(NTHR, 1)
void enc_kernel(const float* __restrict__ xb, const h16* __restrict__ w16enc,
                const float* __restrict__ bencp, unsigned int* __restrict__ encw,
                float* __restrict__ hT) {
  __shared__ alignas(16) h16 sh_hx[2][16][HXS];

  const int t  = threadIdx.x;
  const int r0 = blockIdx.x * EROWS;

  for (int i = t; i < 2 * 16 * HXS; i += NTHR) ((h16*)sh_hx)[i] = (h16)0.f;
  __syncthreads();
  if (t < EROWS * NF) {
    int r = t / NF, f = t - (t / NF) * NF;
    sh_hx[0][r][f] = (h16)xb[((size_t)(r0 + r) * SEQ + 0) * NF + f];
  }

  const int w  = t >> 6;
  const int l  = t & 63;
  const int lq = l >> 4;
  const int ln = l & 15;
  const int hcol = w * 16 + ln;
  const int mrow = lq * 4;
  const bool act = (lq < 2);

  const int j  = t & 3;
  const int rf = t >> 2;
  const int xr = rf / NF;
  const int xf = rf - xr * NF;

  h16x8 bfE[4][5];
  float bE[4];
  #pragma unroll
  for (int g = 0; g < 4; ++g) {
    int n = g * 128 + hcol;
    bE[g] = bencp[n];
    #pragma unroll
    for (int kt = 0; kt < 5; ++kt)
      bfE[g][kt] = *(const h16x8*)(w16enc + n * KE + kt * 32 + lq * 8);
  }

  float creg[4] = {0.f, 0.f, 0.f, 0.f};
  float hlast[4] = {0.f, 0.f, 0.f, 0.f};
  float hprev[4] = {0.f, 0.f, 0.f, 0.f};
  unsigned int hpack[4] = {0u, 0u, 0u, 0u};
  float xstash = 0.f;

  __syncthreads();

  for (int s = 0; s < SEQ; ++s) {
    const int cur = s & 1;
    if ((s & 3) == 0 && t < EROWS * NF * 4) {
      int sx = s + 1 + j;
      xstash = (sx < SEQ) ? xb[((size_t)(r0 + xr) * SEQ + sx) * NF + xf] : 0.f;
    }

    h16x8 af[5];
    #pragma unroll
    for (int kt = 0; kt < 5; ++kt)
      af[kt] = *(const h16x8*)(&sh_hx[cur][ln][kt * 32 + lq * 8]);
    f32x4 ac[4];
    #pragma unroll
    for (int g = 0; g < 4; ++g) {
      f32x4 a = {0.f, 0.f, 0.f, 0.f};
      #pragma unroll
      for (int kt = 0; kt < 5; ++kt)
        a = __builtin_amdgcn_mfma_f32_16x16x32_f16(af[kt], bfE[g][kt], a, 0, 0, 0);
      ac[g] = a;
    }

    if (act) {
      #pragma unroll
      for (int reg = 0; reg < 4; ++reg) {
        float gi = sigm(ac[0][reg] + bE[0]);
        float gf = sigm(ac[1][reg] + bE[1]);
        float gg = tanh_(ac[2][reg] + bE[2]);
        float go = sigm(ac[3][reg] + bE[3]);
        float c = gf * creg[reg] + gi * gg;
        creg[reg] = c;
        float h = go * tanh_(c);
        hlast[reg] = h;
        sh_hx[cur ^ 1][mrow + reg][8 + hcol] = (h16)h;
        float hs = h * 16.f;
        if ((s & 1) == 0) hprev[reg] = hs;
        else if ((s & 3) == 1) hpack[reg] = pack2_fp8<false>(hprev[reg], hs, hpack[reg]);
        else                   hpack[reg] = pack2_fp8<true>(hprev[reg], hs, hpack[reg]);
      }
      if ((s & 3) == 3) {
        int s4 = s >> 2;
        #pragma unroll
        for (int reg = 0; reg < 4; ++reg)
          encw[((size_t)(r0 + mrow + reg) * NS4 + s4) * NH + hcol] = hpack[reg];
      }
    }
    if (t < EROWS * NF * 4 && (s & 3) == j && s + 1 < SEQ)
      sh_hx[cur ^ 1][xr][xf] = (h16)xstash;
    __syncthreads();
  }

  if (act) {
    #pragma unroll
    for (int reg = 0; reg < 4; ++reg)
      hT[(size_t)(r0 + mrow + reg) * NH + hcol] = hlast[reg];
  }
}

// ===== decoder: 8 rows/block, 256 blocks, ONE pass; hist split LDS(s<96)/L2(s>=96) =====
__global__ __launch_bounds__(NTHR, 1)
void dec_kernel(const float* __restrict__ xb, const float* __restrict__ Watt,
                const float* __restrict__ Wout, const float* __restrict__ bout,
                const h16* __restrict__ w16dec, const h16* __restrict__ weff,
                const float* __restrict__ beffp, const float* __restrict__ wcombp,
                const float* __restrict__ bconstp, const float* __restrict__ bdecp,
                const unsigned int* __restrict__ encw, const float* __restrict__ hT,
                float* __restrict__ out) {
  extern __shared__ char smem[];
  unsigned int* hist = (unsigned int*)(smem + HIST_OFF);   // u32[8][24][128]
  h16*   sh_cath  = (h16*)(smem + CATH_OFF);
  float* sh_attw  = (float*)(smem + ATTW_OFF);             // f32[8][168] e-values
  h16*   sh_watt2 = (h16*)(smem + WAT2_OFF);
  float* sh_d0    = (float*)(smem + D0_OFF);               // f32[8][168]
  float* sh_outp  = (float*)(smem + OUTP_OFF);             // f32[8][8]
  float* sh_yh    = (float*)(smem + YH_OFF);               // f32[56]

  const int t  = threadIdx.x;
  const int r0 = blockIdx.x * DROWS;

  // ---- init LDS ----
  for (int i = t; i < 2 * 16 * CTS; i += NTHR)  sh_cath[i] = (h16)0.f;
  for (int i = t; i < 40 * NH; i += NTHR)       sh_watt2[i] = weff[128 * NH + i];
  {
    const unsigned int* src = encw + (size_t)r0 * NS4 * NH;
    for (int i = t; i < DROWS * NSL * NH; i += NTHR) {
      int r = i / (NSL * NH);
      int rem = i - r * (NSL * NH);
      int s4 = rem >> 7, h = rem & 127;
      hist[(r * NSL + s4) * NH + h] = src[((size_t)r * NS4 + s4) * NH + h];
    }
  }

  const int w  = t >> 6;
  const int l  = t & 63;
  const int lq = l >> 4;
  const int ln = l & 15;
  const int hcol = w * 16 + ln;
  const int mrow = lq * 4;
  const bool act = (lq < 2);   // rows 0..7 real

  // B fragments: dec gates (i,f,g) K=256; Weff tile K=128
  h16x8 bfD[3][8];
  float bD[3];
  #pragma unroll
  for (int g = 0; g < 3; ++g) {
    int n = g * 128 + hcol;
    bD[g] = bdecp[n];
    #pragma unroll
    for (int kt = 0; kt < 8; ++kt)
      bfD[g][kt] = *(const h16x8*)(w16dec + n * KD + kt * 32 + lq * 8);
  }
  h16x8 bfA[4];
  #pragma unroll
  for (int kt = 0; kt < 4; ++kt)
    bfA[kt] = *(const h16x8*)(weff + hcol * NH + kt * 32 + lq * 8);
  const float beffR = beffp[hcol];
  const int s2v = 128 + hcol;
  const float beff2 = (w < 3 && s2v < SEQ) ? beffp[s2v] : 0.f;
  const float wcombR = wcombp[hcol];
  const float bconstv = bconstp[0];

  // cell init from h_T; prev_h into cath[0]
  float creg[4] = {0.f, 0.f, 0.f, 0.f};
  if (act) {
    #pragma unroll
    for (int reg = 0; reg < 4; ++reg) {
      float hv = hT[(size_t)(r0 + mrow + reg) * NH + hcol];
      creg[reg] = hv;
      sh_cath[0 * 16 * CTS + (mrow + reg) * CTS + 128 + hcol] = (h16)hv;
    }
  }
  // yh[r][f] = h_T . W_out[f] + bout[f]
  if (t < DROWS * NF) {
    int r = t / NF, f = t - (t / NF) * NF;
    float a = bout[f];
    const float* wr = Wout + f * NH;
    const float* hp = hT + (size_t)(r0 + r) * NH;
    #pragma unroll 8
    for (int k = 0; k < NH; k += 4) {
      float4 pv = *(const float4*)(hp + k);
      float4 wv = *(const float4*)(wr + k);
      a += pv.x * wv.x + pv.y * wv.y + pv.z * wv.z + pv.w * wv.w;
    }
    sh_yh[t] = a;
  }
  __syncthreads();
  // d0[r][s] = (y0[r] - yh[r]) . W_att_y[s]
  for (int i = t; i < DROWS * SEQ; i += NTHR) {
    int r = i / SEQ, s = i - (i / SEQ) * SEQ;
    float a = 0.f;
    #pragma unroll
    for (int f = 0; f < NF; ++f) {
      float y0f = xb[((size_t)(r0 + r) * SEQ + (SEQ - 1)) * NF + f];
      a += (y0f - sh_yh[r * NF + f]) * Watt[s * (NH + NF) + NH + f];
    }
    sh_d0[i] = a;
  }
  __syncthreads();

  // D3 per-thread constants: thread owns (row dr, h-pair 2*h2, 2*h2+1)
  const int dr = t >> 6;
  const int h2 = t & 63;
  const uint2* hl = (const uint2*)hist + (size_t)dr * NSL * 64 + h2;
  const uint2* gl = (const uint2*)encw + ((size_t)(r0 + dr) * NS4 + NSL) * 64 + h2;
  const float* erow = sh_attw + dr * SEQ;

  for (int p = 0; p < NP; ++p) {
    const int CA = p & 1;

    // finalize previous step's output
    if (p > 0 && t < DROWS) {
      float a = bconstv;
      #pragma unroll
      for (int w2 = 0; w2 < 8; ++w2) a += sh_outp[w2 * 8 + t];
      out[(size_t)(r0 + t) * NP + (p - 1)] = a;
    }

    // D1: logits = prev_h @ Weff^T + beff (+d0 @p0); e = exp(clamped)
    {
      h16x8 afA[4];
      #pragma unroll
      for (int kt = 0; kt < 4; ++kt)
        afA[kt] = *(const h16x8*)(sh_cath + CA * 16 * CTS + ln * CTS + 128 + kt * 32 + lq * 8);
      f32x4 acc = {0.f, 0.f, 0.f, 0.f};
      #pragma unroll
      for (int kt = 0; kt < 4; ++kt)
        acc = __builtin_amdgcn_mfma_f32_16x16x32_f16(afA[kt], bfA[kt], acc, 0, 0, 0);
      if (act) {
        #pragma unroll
        for (int reg = 0; reg < 4; ++reg) {
          float lg = acc[reg] + beffR;
          if (p == 0) lg += sh_d0[(mrow + reg) * SEQ + hcol];
          lg = fminf(fmaxf(lg, -30.f), 30.f);
          sh_attw[(mrow + reg) * SEQ + hcol] = __expf(lg);
        }
      }
      if (w < 3) {
        int srow = (s2v < SEQ ? s2v : SEQ - 1) - 128;
        f32x4 acc2 = {0.f, 0.f, 0.f, 0.f};
        #pragma unroll
        for (int kt = 0; kt < 4; ++kt) {
          h16x8 bf2 = *(const h16x8*)(sh_watt2 + srow * NH + kt * 32 + lq * 8);
          acc2 = __builtin_amdgcn_mfma_f32_16x16x32_f16(afA[kt], bf2, acc2, 0, 0, 0);
        }
        if (s2v < SEQ && act) {
          #pragma unroll
          for (int reg = 0; reg < 4; ++reg) {
            float lg = acc2[reg] + beff2;
            if (p == 0) lg += sh_d0[(mrow + reg) * SEQ + s2v];
            lg = fminf(fmaxf(lg, -30.f), 30.f);
            sh_attw[(mrow + reg) * SEQ + s2v] = __expf(lg);
          }
        }
      }
    }
    __syncthreads();

    // D3: combine[r][h] = (Σ_s e_s v_s)/(Σ_s e_s); thread owns (r, 2 h's)
    {
      // issue the L2/global part loads up-front (latency-hidden under LDS compute)
      uint2 gv[NSG];
      #pragma unroll
      for (int jj = 0; jj < NSG; ++jj) gv[jj] = gl[jj * 64];

      f32x2 av0 = {0.f, 0.f}, av1 = {0.f, 0.f}, es = {0.f, 0.f};
      #pragma unroll 6
      for (int jj = 0; jj < NSL; ++jj) {
        uint2 ev = hl[jj * 64];
        float4 e4 = *(const float4*)(erow + jj * 4);   // broadcast
        f32x2 e01 = {e4.x, e4.y}, e23 = {e4.z, e4.w};
        f32x2 p0 = unp2<false>(ev.x), p1 = unp2<true>(ev.x);
        f32x2 q0 = unp2<false>(ev.y), q1 = unp2<true>(ev.y);
        av0 += e01 * p0; av0 += e23 * p1;
        av1 += e01 * q0; av1 += e23 * q1;
        es  += e01;      es  += e23;
      }
      #pragma unroll
      for (int jj = 0; jj < NSG; ++jj) {
        uint2 ev = gv[jj];
        float4 e4 = *(const float4*)(erow + (NSL + jj) * 4);
        f32x2 e01 = {e4.x, e4.y}, e23 = {e4.z, e4.w};
        f32x2 p0 = unp2<false>(ev.x), p1 = unp2<true>(ev.x);
        f32x2 q0 = unp2<false>(ev.y), q1 = unp2<true>(ev.y);
        av0 += e01 * p0; av0 += e23 * p1;
        av1 += e01 * q0; av1 += e23 * q1;
        es  += e01;      es  += e23;
      }
      float inv = 0.0625f / (es.x + es.y);
      h16x2 cv;
      cv[0] = (h16)((av0.x + av0.y) * inv);
      cv[1] = (h16)((av1.x + av1.y) * inv);
      *(h16x2*)(sh_cath + CA * 16 * CTS + dr * CTS + 2 * h2) = cv;
    }
    __syncthreads();

    // D4+D5: gates via MFMA (i,f,g); cell in-register; out-partials via wcomb
    {
      h16x8 af[8];
      #pragma unroll
      for (int kt = 0; kt < 8; ++kt)
        af[kt] = *(const h16x8*)(sh_cath + CA * 16 * CTS + ln * CTS + kt * 32 + lq * 8);
      f32x4 ag[3];
      #pragma unroll
      for (int g = 0; g < 3; ++g) {
        f32x4 a = {0.f, 0.f, 0.f, 0.f};
        #pragma unroll
        for (int kt = 0; kt < 8; ++kt)
          a = __builtin_amdgcn_mfma_f32_16x16x32_f16(af[kt], bfD[g][kt], a, 0, 0, 0);
        ag[g] = a;
      }
      if (act) {
        float contrib[4];
        #pragma unroll
        for (int reg = 0; reg < 4; ++reg) {
          float gi = sigm(ag[0][reg] + bD[0]);
          float gf = sigm(ag[1][reg] + bD[1]);
          float gg = tanh_(ag[2][reg] + bD[2]);
          float cn = gf * creg[reg] + gi * gg;
          creg[reg] = cn;
          sh_cath[(CA ^ 1) * 16 * CTS + (mrow + reg) * CTS + 128 + hcol] = (h16)cn;
          contrib[reg] = cn * wcombR;
        }
        #pragma unroll
        for (int reg = 0; reg < 4; ++reg) {
          float rsum = contrib[reg];
          rsum += __shfl_xor(rsum, 1);
          rsum += __shfl_xor(rsum, 2);
          rsum += __shfl_xor(rsum, 4);
          rsum += __shfl_xor(rsum, 8);
          if (ln == 0) sh_outp[w * 8 + mrow + reg] = rsum;
        }
      }
    }
    __syncthreads();
  }

  // finalize last output
  if (t < DROWS) {
    float a = bconstv;
    #pragma unroll
    for (int w2 = 0; w2 < 8; ++w2) a += sh_outp[w2 * 8 + t];
    out[(size_t)(r0 + t) * NP + (NP - 1)] = a;
  }
}

extern "C" void kernel_launch(void* const* d_in, const int* in_sizes, int n_in,
                              void* d_out, int out_size, void* d_ws, size_t ws_size,
                              hipStream_t stream) {
  const float* xb      = (const float*)d_in[0];
  const float* Wih_enc = (const float*)d_in[1];
  const float* Whh_enc = (const float*)d_in[2];
  const float* bih_enc = (const float*)d_in[3];
  const float* bhh_enc = (const float*)d_in[4];
  const float* Watt    = (const float*)d_in[5];
  const float* batt    = (const float*)d_in[6];
  const float* Wih_dec = (const float*)d_in[7];
  const float* Whh_dec = (const float*)d_in[8];
  const float* bih_dec = (const float*)d_in[9];
  const float* bhh_dec = (const float*)d_in[10];
  const float* Wout    = (const float*)d_in[11];
  const float* bout    = (const float*)d_in[12];
  const float* Wfin    = (const float*)d_in[13];
  const float* bfin    = (const float*)d_in[14];
  char* ws = (char*)d_ws;  // needs ~45.6 MB

  hipFuncSetAttribute(reinterpret_cast<const void*>(dec_kernel),
                      hipFuncAttributeMaxDynamicSharedMemorySize, DSMEM);

  setup_weights<<<920, 256, 0, stream>>>(Wih_enc, Whh_enc, Wih_dec, Whh_dec,
                                         Watt, batt, Wout, bout, Wfin, bfin,
                                         bih_enc, bhh_enc, bih_dec, bhh_dec, ws);
  enc_kernel<<<NB / EROWS, NTHR, 0, stream>>>(
      xb, (const h16*)(ws + WENC_OFF), (const float*)(ws + BENC_OFF),
      (unsigned int*)(ws + ENC_OFF), (float*)(ws + HT_OFF));
  dec_kernel<<<NB / DROWS, NTHR, DSMEM, stream>>>(
      xb, Watt, Wout, bout,
      (const h16*)(ws + WDEC_OFF), (const h16*)(ws + WEFF_OFF),
      (const float*)(ws + BEFF_OFF), (const float*)(ws + WCOMB_OFF),
      (const float*)(ws + BCONST_OFF), (const float*)(ws + BDEC_OFF),
      (const unsigned int*)(ws + ENC_OFF), (const float*)(ws + HT_OFF),
      (float*)d_out);
}